// Round 1
// baseline (1882.011 us; speedup 1.0000x reference)
//
#include <hip/hip_runtime.h>
#include <hip/hip_bf16.h>

#define NCLASS 19
#define CHUNK 2048
#define IGNORE_IDX (-100)

// ---------------------------------------------------------------------------
// Phase 1: per-pixel softmax + packed (pos<<32 | neg) histogram over err bins.
// err in [0,1]; bin = floor(err*B) clamped to [0,B-1].
// ---------------------------------------------------------------------------
__global__ void __launch_bounds__(256) lovasz_hist(
    const float* __restrict__ logits, const int* __restrict__ labels,
    unsigned long long* __restrict__ hist, int B, int P, int HW) {
  int p = blockIdx.x * blockDim.x + threadIdx.x;
  if (p >= P) return;
  int n = p / HW;
  int hw = p - n * HW;
  const float* lp = logits + (size_t)n * NCLASS * (size_t)HW + hw;

  float v[NCLASS];
  float m = -3.4e38f;
#pragma unroll
  for (int c = 0; c < NCLASS; ++c) {
    v[c] = lp[(size_t)c * HW];
    m = fmaxf(m, v[c]);
  }
  float s = 0.f;
#pragma unroll
  for (int c = 0; c < NCLASS; ++c) {
    v[c] = expf(v[c] - m);
    s += v[c];
  }
  float inv = 1.0f / s;

  int lb = labels[p];
  if (lb == IGNORE_IDX) return;  // ignored pixels contribute nothing (t>0)

  float fB = (float)B;
#pragma unroll
  for (int c = 0; c < NCLASS; ++c) {
    float prob = v[c] * inv;
    bool pos = (c == lb);
    float e = pos ? (1.0f - prob) : prob;
    int b = (int)(e * fB);
    b = b < 0 ? 0 : (b >= B ? B - 1 : b);
    atomicAdd(hist + (size_t)c * B + b, pos ? (1ull << 32) : 1ull);
  }
}

// ---------------------------------------------------------------------------
// Phase 2a: per-(class,chunk) totals of packed counts (u64 sums stay packed:
// both sub-counts < 2^32).
// ---------------------------------------------------------------------------
__global__ void __launch_bounds__(256) lovasz_chunk_tot(
    const unsigned long long* __restrict__ hist,
    unsigned long long* __restrict__ chunkTot, int B, int nch) {
  int c = blockIdx.x / nch;
  int ch = blockIdx.x - c * nch;
  const unsigned long long* h = hist + (size_t)c * B + (size_t)ch * CHUNK;
  unsigned long long acc = 0;
  for (int i = threadIdx.x; i < CHUNK; i += blockDim.x) acc += h[i];
  for (int off = 32; off > 0; off >>= 1) acc += __shfl_down(acc, off, 64);
  __shared__ unsigned long long sm[4];
  int lane = threadIdx.x & 63, w = threadIdx.x >> 6;
  if (lane == 0) sm[w] = acc;
  __syncthreads();
  if (threadIdx.x == 0) {
    unsigned long long t = 0;
    for (int i = 0; i < 4; ++i) t += sm[i];
    chunkTot[c * nch + ch] = t;
  }
}

// ---------------------------------------------------------------------------
// Phase 2b: per-class exclusive suffix offsets over chunk totals (+ totals).
// 19 blocks x 64 threads; nch <= 64.
// ---------------------------------------------------------------------------
__global__ void __launch_bounds__(64) lovasz_chunk_off(
    const unsigned long long* __restrict__ chunkTot,
    unsigned long long* __restrict__ chunkOff,
    unsigned long long* __restrict__ totals, int nch) {
  int c = blockIdx.x;
  __shared__ unsigned long long sm[64];
  int i = threadIdx.x;
  sm[i] = (i < nch) ? chunkTot[c * nch + i] : 0ull;
  __syncthreads();
  if (i < nch) {
    unsigned long long off = 0;
    for (int j = i + 1; j < nch; ++j) off += sm[j];
    chunkOff[c * nch + i] = off;
    if (i == 0) totals[c] = off + sm[0];
  }
}

// ---------------------------------------------------------------------------
// Phase 2c: per-(class,chunk) suffix scan over bins; accumulate J per bin.
// loss_c = (1/B) * sum_{b>=1} J_b,  J_b = union>0 ? 1 - (nPos-CP)/(nPos+CN) : 0
// where (CP,CN) are inclusive suffix counts at bin b.
// ---------------------------------------------------------------------------
__global__ void __launch_bounds__(256) lovasz_scan(
    const unsigned long long* __restrict__ hist,
    const unsigned long long* __restrict__ chunkOff,
    const unsigned long long* __restrict__ totals,
    float* __restrict__ partial, int B, int nch) {
  int c = blockIdx.x / nch;
  int ch = blockIdx.x - c * nch;
  int baseBin = ch * CHUNK;
  const unsigned long long* h = hist + (size_t)c * B + baseBin;
  unsigned long long above = chunkOff[c * nch + ch];
  float nPos = (float)(unsigned)(totals[c] >> 32);

  __shared__ unsigned long long arr[256];
  __shared__ float smf[4];
  int tid = threadIdx.x;
  float acc = 0.f;

  for (int r = 0; r < CHUNK / 256; ++r) {
    int rlo = CHUNK - 256 * (r + 1);  // rows from the top (descending bins)
    arr[tid] = h[rlo + tid];
    __syncthreads();
    // inclusive suffix scan (Hillis-Steele) on packed u64
    for (int off = 1; off < 256; off <<= 1) {
      unsigned long long add = (tid + off < 256) ? arr[tid + off] : 0ull;
      __syncthreads();
      arr[tid] += add;
      __syncthreads();
    }
    unsigned long long suff = arr[tid] + above;
    unsigned long long rowTot = arr[0];
    __syncthreads();  // everyone read arr before next overwrite

    int gb = baseBin + rlo + tid;
    if (gb >= 1) {
      float CP = (float)(unsigned)(suff >> 32);
      float CN = (float)(unsigned)(suff & 0xffffffffull);
      float uni = nPos + CN;
      if (uni > 0.f) acc += 1.0f - (nPos - CP) / uni;
    }
    above += rowTot;
  }

  for (int off = 32; off > 0; off >>= 1) acc += __shfl_down(acc, off, 64);
  int lane = tid & 63, w = tid >> 6;
  if (lane == 0) smf[w] = acc;
  __syncthreads();
  if (tid == 0) {
    float t = 0.f;
    for (int i = 0; i < 4; ++i) t += smf[i];
    partial[c * nch + ch] = t;
  }
}

// ---------------------------------------------------------------------------
// Phase 3: fixed-order reduction of partials -> mean loss.
// ---------------------------------------------------------------------------
__global__ void __launch_bounds__(256) lovasz_final(
    const float* __restrict__ partial, float* __restrict__ out, int n,
    float scale) {
  float acc = 0.f;
  for (int i = threadIdx.x; i < n; i += blockDim.x) acc += partial[i];
  for (int off = 32; off > 0; off >>= 1) acc += __shfl_down(acc, off, 64);
  __shared__ float sm[4];
  int lane = threadIdx.x & 63, w = threadIdx.x >> 6;
  if (lane == 0) sm[w] = acc;
  __syncthreads();
  if (threadIdx.x == 0) {
    float t = 0.f;
    for (int i = 0; i < 4; ++i) t += sm[i];
    out[0] = t * scale;
  }
}

extern "C" void kernel_launch(void* const* d_in, const int* in_sizes, int n_in,
                              void* d_out, int out_size, void* d_ws,
                              size_t ws_size, hipStream_t stream) {
  const float* logits = (const float*)d_in[0];
  const int* labels = (const int*)d_in[1];
  float* out = (float*)d_out;

  const int P = in_sizes[1];       // 8*512*512 = 2,097,152 pixels
  const int HW = 512 * 512;        // per-image spatial size

  // Pick histogram resolution that fits the workspace (meta needs < 64 KB).
  int B = 1 << 17;
  while (B > (1 << 13) &&
         (size_t)NCLASS * B * 8 + 65536 > ws_size)
    B >>= 2;  // 2^17 -> 2^15 -> 2^13 (nch = 64 / 16 / 4)
  const int nch = B / CHUNK;

  char* ws = (char*)d_ws;
  size_t histBytes = (size_t)NCLASS * B * 8;
  unsigned long long* hist = (unsigned long long*)ws;
  unsigned long long* chunkTot = (unsigned long long*)(ws + histBytes);
  unsigned long long* chunkOff = chunkTot + NCLASS * 64;
  unsigned long long* totals = chunkOff + NCLASS * 64;
  float* partial = (float*)(totals + NCLASS);

  hipMemsetAsync(d_ws, 0, histBytes, stream);

  int blocks1 = (P + 255) / 256;
  lovasz_hist<<<blocks1, 256, 0, stream>>>(logits, labels, hist, B, P, HW);
  lovasz_chunk_tot<<<NCLASS * nch, 256, 0, stream>>>(hist, chunkTot, B, nch);
  lovasz_chunk_off<<<NCLASS, 64, 0, stream>>>(chunkTot, chunkOff, totals, nch);
  lovasz_scan<<<NCLASS * nch, 256, 0, stream>>>(hist, chunkOff, totals, partial,
                                                B, nch);
  lovasz_final<<<1, 256, 0, stream>>>(partial, out, NCLASS * nch,
                                      1.0f / ((float)B * (float)NCLASS));
}

// Round 2
// 66.165 us; speedup vs baseline: 28.4443x; 28.4443x over previous
//
#include <hip/hip_runtime.h>
#include <hip/hip_bf16.h>

#define NCLASS 19
#define BINS 1024
#define NB (NCLASS * BINS)   // 19456 bins total
#define SLICES 8
#define IGNORE_IDX (-100)

// ---------------------------------------------------------------------------
// Phase 1: per-pixel softmax; privatized per-block LDS histogram, u32-packed
// (pos<<16 | neg). Each block writes its full copy to ws (plain stores, no
// global atomics). Counts per block <= ppb <= 16384 -> fields never overflow.
// ---------------------------------------------------------------------------
__global__ void __launch_bounds__(512) hist_lds(
    const float* __restrict__ logits, const int* __restrict__ labels,
    unsigned* __restrict__ copies, int P, int HW, int ppb) {
  extern __shared__ unsigned sh[];  // NB u32 = 76 KB
  for (int i = threadIdx.x; i < NB; i += blockDim.x) sh[i] = 0u;
  __syncthreads();

  int p0 = blockIdx.x * ppb;
  int p1 = min(P, p0 + ppb);
  for (int p = p0 + (int)threadIdx.x; p < p1; p += blockDim.x) {
    int n = p / HW;
    int hw = p - n * HW;
    const float* lp = logits + (size_t)n * NCLASS * (size_t)HW + hw;

    float v[NCLASS];
    float m = -3.4e38f;
#pragma unroll
    for (int c = 0; c < NCLASS; ++c) {
      v[c] = lp[(size_t)c * HW];
      m = fmaxf(m, v[c]);
    }
    float s = 0.f;
#pragma unroll
    for (int c = 0; c < NCLASS; ++c) {
      v[c] = __expf(v[c] - m);
      s += v[c];
    }
    float inv = 1.0f / s;

    int lb = labels[p];
    if (lb == IGNORE_IDX) continue;  // contributes to nothing

#pragma unroll
    for (int c = 0; c < NCLASS; ++c) {
      float prob = v[c] * inv;
      bool pos = (c == lb);
      float e = pos ? (1.0f - prob) : prob;
      int b = (int)(e * (float)BINS);
      b = b < 0 ? 0 : (b >= BINS ? BINS - 1 : b);
      atomicAdd(&sh[c * BINS + b], pos ? 0x10000u : 1u);
    }
  }
  __syncthreads();

  unsigned* dst = copies + (size_t)blockIdx.x * NB;
  for (int i = threadIdx.x; i < NB; i += blockDim.x) dst[i] = sh[i];
}

// ---------------------------------------------------------------------------
// Phase 2a: partial tree-reduce of the R copies: slice s sums copies r==s
// (mod SLICES) into u64 packed (pos<<32 | neg). Coalesced, no atomics.
// ---------------------------------------------------------------------------
__global__ void __launch_bounds__(256) reduce_part(
    const unsigned* __restrict__ copies, unsigned long long* __restrict__ part,
    int R) {
  const int nblk = NB / 256;  // 76
  int s = blockIdx.x / nblk;
  int blk = blockIdx.x - s * nblk;
  int cb = blk * 256 + threadIdx.x;
  unsigned long long acc = 0;
  for (int r = s; r < R; r += SLICES) {
    unsigned v = copies[(size_t)r * NB + cb];
    acc += ((unsigned long long)(v >> 16) << 32) | (unsigned long long)(v & 0xffffu);
  }
  part[(size_t)s * NB + cb] = acc;
}

// ---------------------------------------------------------------------------
// Phase 2b: sum the SLICES partials into the final u64 histogram.
// ---------------------------------------------------------------------------
__global__ void __launch_bounds__(256) reduce_hist(
    const unsigned long long* __restrict__ part,
    unsigned long long* __restrict__ hist) {
  int cb = blockIdx.x * 256 + threadIdx.x;
  unsigned long long acc = 0;
#pragma unroll
  for (int s = 0; s < SLICES; ++s) acc += part[(size_t)s * NB + cb];
  hist[cb] = acc;
}

// ---------------------------------------------------------------------------
// Fallback phase 1 (tiny ws): direct global u64 atomics (slow but correct).
// ---------------------------------------------------------------------------
__global__ void __launch_bounds__(256) hist_global(
    const float* __restrict__ logits, const int* __restrict__ labels,
    unsigned long long* __restrict__ hist, int P, int HW) {
  int p = blockIdx.x * blockDim.x + threadIdx.x;
  if (p >= P) return;
  int n = p / HW;
  int hw = p - n * HW;
  const float* lp = logits + (size_t)n * NCLASS * (size_t)HW + hw;
  float v[NCLASS];
  float m = -3.4e38f;
#pragma unroll
  for (int c = 0; c < NCLASS; ++c) {
    v[c] = lp[(size_t)c * HW];
    m = fmaxf(m, v[c]);
  }
  float s = 0.f;
#pragma unroll
  for (int c = 0; c < NCLASS; ++c) {
    v[c] = __expf(v[c] - m);
    s += v[c];
  }
  float inv = 1.0f / s;
  int lb = labels[p];
  if (lb == IGNORE_IDX) return;
#pragma unroll
  for (int c = 0; c < NCLASS; ++c) {
    float prob = v[c] * inv;
    bool pos = (c == lb);
    float e = pos ? (1.0f - prob) : prob;
    int b = (int)(e * (float)BINS);
    b = b < 0 ? 0 : (b >= BINS ? BINS - 1 : b);
    atomicAdd(hist + c * BINS + b, pos ? (1ull << 32) : 1ull);
  }
}

// ---------------------------------------------------------------------------
// Phase 3: per-class suffix scan over BINS bins; J accumulation.
// loss_c = (1/BINS) * sum_{b>=1} J_b; J_b from inclusive suffix counts at b.
// ---------------------------------------------------------------------------
__global__ void __launch_bounds__(256) scan19(
    const unsigned long long* __restrict__ hist, float* __restrict__ partial) {
  int c = blockIdx.x;
  __shared__ unsigned long long bins[BINS];
  __shared__ unsigned long long arr[256];
  __shared__ unsigned long long wsum[4];
  __shared__ float fsum[4];
  int tid = threadIdx.x;

  for (int i = tid; i < BINS; i += 256) bins[i] = hist[c * BINS + i];
  __syncthreads();

  // total (for nPos)
  unsigned long long t = 0;
  for (int i = tid; i < BINS; i += 256) t += bins[i];
  for (int off = 32; off > 0; off >>= 1) t += __shfl_down(t, off, 64);
  int lane = tid & 63, w = tid >> 6;
  if (lane == 0) wsum[w] = t;
  __syncthreads();
  unsigned long long total = wsum[0] + wsum[1] + wsum[2] + wsum[3];
  float nPos = (float)(unsigned)(total >> 32);

  // suffix scan, rows descending, with carry `above`
  unsigned long long above = 0;
  float acc = 0.f;
  for (int r = BINS / 256 - 1; r >= 0; --r) {
    arr[tid] = bins[r * 256 + tid];
    __syncthreads();
    for (int off = 1; off < 256; off <<= 1) {
      unsigned long long add = (tid + off < 256) ? arr[tid + off] : 0ull;
      __syncthreads();
      arr[tid] += add;
      __syncthreads();
    }
    unsigned long long suff = arr[tid] + above;
    unsigned long long rowTot = arr[0];
    __syncthreads();

    int gb = r * 256 + tid;
    if (gb >= 1) {
      float CP = (float)(unsigned)(suff >> 32);
      float CN = (float)(unsigned)(suff & 0xffffffffull);
      float uni = nPos + CN;
      if (uni > 0.f) acc += 1.0f - (nPos - CP) / uni;
    }
    above += rowTot;
  }

  for (int off = 32; off > 0; off >>= 1) acc += __shfl_down(acc, off, 64);
  if (lane == 0) fsum[w] = acc;
  __syncthreads();
  if (tid == 0) partial[c] = fsum[0] + fsum[1] + fsum[2] + fsum[3];
}

// ---------------------------------------------------------------------------
// Phase 4: mean over classes.
// ---------------------------------------------------------------------------
__global__ void __launch_bounds__(64) lovasz_final(
    const float* __restrict__ partial, float* __restrict__ out, int n,
    float scale) {
  float acc = 0.f;
  for (int i = threadIdx.x; i < n; i += 64) acc += partial[i];
  for (int off = 32; off > 0; off >>= 1) acc += __shfl_down(acc, off, 64);
  if (threadIdx.x == 0) out[0] = acc * scale;
}

extern "C" void kernel_launch(void* const* d_in, const int* in_sizes, int n_in,
                              void* d_out, int out_size, void* d_ws,
                              size_t ws_size, hipStream_t stream) {
  const float* logits = (const float*)d_in[0];
  const int* labels = (const int*)d_in[1];
  float* out = (float*)d_out;

  const int P = in_sizes[1];  // 8*512*512
  const int HW = 512 * 512;

  char* ws = (char*)d_ws;

  // Pick privatization factor R that fits ws (min 128 keeps u16 fields safe).
  int R = 0;
  for (int r = 512; r >= 128; r >>= 1) {
    size_t need = (size_t)r * NB * 4 + (size_t)SLICES * NB * 8 +
                  (size_t)NB * 8 + 4096;
    if (need <= ws_size) { R = r; break; }
  }

  if (R) {
    unsigned* copies = (unsigned*)ws;
    unsigned long long* part =
        (unsigned long long*)(ws + (size_t)R * NB * 4);
    unsigned long long* hist = part + (size_t)SLICES * NB;
    float* partial = (float*)(hist + NB);
    int ppb = (P + R - 1) / R;

    hist_lds<<<R, 512, NB * 4, stream>>>(logits, labels, copies, P, HW, ppb);
    reduce_part<<<SLICES * (NB / 256), 256, 0, stream>>>(copies, part, R);
    reduce_hist<<<NB / 256, 256, 0, stream>>>(part, hist);
    scan19<<<NCLASS, 256, 0, stream>>>(hist, partial);
    lovasz_final<<<1, 64, 0, stream>>>(partial, out, NCLASS,
                                       1.0f / ((float)BINS * (float)NCLASS));
  } else {
    // Tiny-ws fallback: direct global atomics into u64 hist.
    unsigned long long* hist = (unsigned long long*)ws;
    float* partial = (float*)(hist + NB);
    hipMemsetAsync(d_ws, 0, (size_t)NB * 8, stream);
    hist_global<<<(P + 255) / 256, 256, 0, stream>>>(logits, labels, hist, P,
                                                     HW);
    scan19<<<NCLASS, 256, 0, stream>>>(hist, partial);
    lovasz_final<<<1, 64, 0, stream>>>(partial, out, NCLASS,
                                       1.0f / ((float)BINS * (float)NCLASS));
  }
}